// Round 3
// baseline (55.891 us; speedup 1.0000x reference)
//
#include <hip/hip_runtime.h>

// ---------------- problem constants ----------------
#define NC    2
#define NB    9
#define NNODE 820
#define NL    3
#define NK    17

#define SQRT2F   1.41421356237309515f
#define ISQ2PIF  0.3989422804014327f    // 1/sqrt(2*pi)
#define I2PIF    0.15915494309189535f   // 1/(2*pi)
#define EPSF     1e-30f

// output layout (flat f32 offsets, concatenated in reference return order)
#define OFF_XN    0LL
#define OFF_XE    752760LL
#define OFF_LPN   26315388LL
#define OFF_LPE   27068148LL
#define OFF_ALPHA 39849462LL
#define OFF_O1    39849516LL
#define OFF_O2    39893742LL

typedef float v2f __attribute__((ext_vector_type(2)));

// ---------------- compile-time Gauss-Hermite nodes (n=17) ----------------
// Same NR 'gauher' Newton algorithm the runtime kernel used, but evaluated
// entirely at compile time (constexpr). Initial guesses only need ~1e-3
// accuracy (Newton in fp64 converges to <3e-14); the two pow() constants are
// hardcoded: 35^(-0.16667)=0.552905, 17^(0.426)=3.34327.
constexpr double csqrt(double v) {
    if (v <= 0.0) return 0.0;
    double y = v > 1.0 ? v : 1.0;
    for (int i = 0; i < 80; ++i) y = 0.5 * (y + v / y);
    return y;
}

struct HNodesF { float x[NK]; };

constexpr HNodesF compute_nodes() {
    const int n = NK;
    const double PIM4 = 0.7511255444649425;   // pi^{-1/4}
    double c1[NK + 1] = {}, c2[NK + 1] = {};
    for (int j = 1; j <= n; ++j) {
        c1[j] = csqrt(2.0 / (double)j);
        c2[j] = csqrt(((double)j - 1.0) / (double)j);
    }
    const double PPC = csqrt(2.0 * (double)n);
    double xr[9] = {};
    double z = 0.0;
    for (int i = 0; i < 9; ++i) {
        if (i == 0)      z = csqrt(2.0 * n + 1.0) - 1.85575 * 0.552905;
        else if (i == 1) z -= 1.14 * 3.34327 / z;
        else if (i == 2) z = 1.86 * z - 0.86 * xr[0];
        else if (i == 3) z = 1.91 * z - 0.91 * xr[1];
        else             z = 2.0 * z - xr[i - 2];
        for (int it = 0; it < 24; ++it) {
            double p1 = PIM4, p2 = 0.0;
            for (int j = 1; j <= n; ++j) {
                double p3 = p2;
                p2 = p1;
                p1 = z * c1[j] * p2 - c2[j] * p3;
            }
            double pp = PPC * p2;
            double z1 = z;
            z = z1 - p1 / pp;
            double d = z - z1; if (d < 0.0) d = -d;
            if (d <= 3.0e-14) break;
        }
        xr[i] = z;   // descending positive roots, xr[8] ~ 0
    }
    HNodesF f{};
    for (int i = 0; i < 9; ++i) {
        f.x[16 - i] = (float)xr[i];          // ascending like numpy hermgauss
        f.x[i]      = (float)(-xr[i]);
    }
    return f;
}

constexpr HNodesF HNF = compute_nodes();

__device__ __forceinline__ float sel3(float a0, float a1, float a2, int i) {
    float r = a0;
    r = (i == 1) ? a1 : r;
    r = (i == 2) ? a2 : r;
    return r;
}

// ---------------- single fused kernel: xn, lpn, xe, lpe, o1, o2, alpha ----------------
// grid = NC*NB*820 blocks; block (cb, n). Blocks with n < 819 also do the
// edge (xe/lpe/o1/o2) work for pair index (cb, n). Block 0 writes alpha.
// All output stores are nontemporal: outputs are write-once streams, never
// re-read — nt bypasses L2 allocation (avoids read-for-ownership traffic).
__global__ __launch_bounds__(256) void fused_kernel(const float* __restrict__ mu,
                                                    const float* __restrict__ sigma,
                                                    const float* __restrict__ w,
                                                    float* __restrict__ out) {
    int bid = blockIdx.x;            // cb*820 + n
    int tid = threadIdx.x;
    int cb  = bid / NNODE;           // 0..17
    int n   = bid - cb * NNODE;      // 0..819
    int b   = cb % NB;

    __shared__ float snd[NK];
    if (tid < NK) snd[tid] = HNF.x[tid];

    const float* muN = mu    + (size_t)bid * 3;
    const float* sgN = sigma + (size_t)bid * 3;
    const float* wB  = w + cb * 3;

    float u1a = muN[0], u1b = muN[1], u1c = muN[2];
    float s1a = sgN[0], s1b = sgN[1], s1c = sgN[2];

    float w0 = wB[0], w1 = wB[1], w2 = wB[2];
    float wm = fmaxf(w0, fmaxf(w1, w2));
    float e0 = __expf(w0 - wm), e1 = __expf(w1 - wm), e2 = __expf(w2 - wm);
    float inv = 1.0f / (e0 + e1 + e2);
    float a0 = e0 * inv, a1 = e1 * inv, a2 = e2 * inv;

    float i1a = 1.0f / s1a, i1b = 1.0f / s1b, i1c = 1.0f / s1c;

    bool masked = (b >= 1) && (n < 729);

    __syncthreads();

    // ---- xn + lpn (threads 0..50) ----
    if (tid < NL * NK) {
        int l1 = tid / NK;
        int k  = tid - l1 * NK;
        float sl = sel3(s1a, s1b, s1c, l1);
        float ul = sel3(u1a, u1b, u1c, l1);
        float xn = fmaf(snd[k] * sl, SQRT2F, ul);
        __builtin_nontemporal_store(xn, out + OFF_XN + (size_t)bid * 51 + tid);

        float lp;
        if (masked) {
            lp = 0.0f;
        } else {
            float d0 = (xn - u1a) * i1a;
            float d1 = (xn - u1b) * i1b;
            float d2 = (xn - u1c) * i1c;
            float sum = (a0 * i1a) * __expf(-0.5f * d0 * d0)
                      + (a1 * i1b) * __expf(-0.5f * d1 * d1)
                      + (a2 * i1c) * __expf(-0.5f * d2 * d2);
            lp = __logf(sum * ISQ2PIF + EPSF);
        }
        __builtin_nontemporal_store(lp, out + OFF_LPN + (size_t)bid * 51 + tid);
    }

    // ---- alpha (block 0, threads 192..245) ----
    if (bid == 0 && tid >= 192 && tid < 192 + NC * NB * NL) {
        int t   = tid - 192;
        int cb2 = t / 3;
        int l   = t - cb2 * 3;
        const float* wB2 = w + cb2 * 3;
        float v0 = wB2[0], v1 = wB2[1], v2 = wB2[2];
        float vm = fmaxf(v0, fmaxf(v1, v2));
        float f0 = __expf(v0 - vm), f1 = __expf(v1 - vm), f2 = __expf(v2 - vm);
        float finv = 1.0f / (f0 + f1 + f2);
        float fl = (l == 0) ? f0 : ((l == 1) ? f1 : f2);
        __builtin_nontemporal_store(fl * finv, out + OFF_ALPHA + t);
    }

    if (n >= 819) return;            // edge work only for n < 819

    // closed-form _ID gather
    int id;
    if (n < 729)      { int a = n / 81;  int r = n % 27; id = 729 + a * 9 + r / 3; }
    else if (n < 810) { int m = n - 729; int a = m / 27; int r = m % 9; id = 810 + a * 3 + r / 3; }
    else              { id = 819; }

    const float* muI = mu    + ((size_t)cb * NNODE + id) * 3;
    const float* sgI = sigma + ((size_t)cb * NNODE + id) * 3;
    float u2a = muI[0], u2b = muI[1], u2c = muI[2];
    float s2a = sgI[0], s2b = sgI[1], s2c = sgI[2];
    float i2a = 1.0f / s2a, i2b = 1.0f / s2b, i2c = 1.0f / s2c;

    float ca, cbv, cc;
    if (masked) {       // b1 -> ones
        ca  = a0 * i2a * ISQ2PIF;
        cbv = a1 * i2b * ISQ2PIF;
        cc  = a2 * i2c * ISQ2PIF;
    } else {
        ca  = a0 * i1a * i2a * I2PIF;
        cbv = a1 * i1b * i2b * I2PIF;
        cc  = a2 * i1c * i2c * I2PIF;
    }

    size_t bid2 = (size_t)cb * 819 + n;

    if (tid >= 64 && tid < 67)
        __builtin_nontemporal_store(sel3(s1a, s1b, s1c, tid - 64), out + OFF_O1 + bid2 * 3 + (tid - 64));
    else if (tid >= 67 && tid < 70)
        __builtin_nontemporal_store(sel3(s2a, s2b, s2c, tid - 67), out + OFF_O2 + bid2 * 3 + (tid - 67));

    v2f*   xe  = reinterpret_cast<v2f*>(out + OFF_XE) + bid2 * 867;
    float* lpe = out + OFF_LPE + bid2 * 867;

    for (int e = tid; e < 867; e += 256) {
        int l1 = e / 289;
        int q  = e - l1 * 289;
        int qj = q / NK;
        int qi = q - qj * NK;
        float xiv = snd[qi];
        float xjv = snd[qj];

        float s1l = sel3(s1a, s1b, s1c, l1);
        float u1l = sel3(u1a, u1b, u1c, l1);
        float s2l = sel3(s2a, s2b, s2c, l1);
        float u2l = sel3(u2a, u2b, u2c, l1);

        float x1 = fmaf(xiv * s1l, SQRT2F, u1l);
        float x2 = fmaf(xjv * s2l, SQRT2F, u2l);
        v2f xv; xv.x = x1; xv.y = x2;
        __builtin_nontemporal_store(xv, xe + e);

        float t0 = (x2 - u2a) * i2a; t0 *= t0;
        float t1 = (x2 - u2b) * i2b; t1 *= t1;
        float t2 = (x2 - u2c) * i2c; t2 *= t2;
        if (!masked) {
            float d0 = (x1 - u1a) * i1a; t0 = fmaf(d0, d0, t0);
            float d1 = (x1 - u1b) * i1b; t1 = fmaf(d1, d1, t1);
            float d2 = (x1 - u1c) * i1c; t2 = fmaf(d2, d2, t2);
        }
        float sum = ca  * __expf(-0.5f * t0)
                  + cbv * __expf(-0.5f * t1)
                  + cc  * __expf(-0.5f * t2);
        __builtin_nontemporal_store(__logf(sum + EPSF), lpe + e);
    }
}

extern "C" void kernel_launch(void* const* d_in, const int* in_sizes, int n_in,
                              void* d_out, int out_size, void* d_ws, size_t ws_size,
                              hipStream_t stream) {
    const float* mu    = (const float*)d_in[0];
    const float* sigma = (const float*)d_in[1];
    const float* w     = (const float*)d_in[2];
    float* out = (float*)d_out;

    hipLaunchKernelGGL(fused_kernel, dim3(NC * NB * NNODE), dim3(256), 0, stream,
                       mu, sigma, w, out);
}

// Round 4
// 33.132 us; speedup vs baseline: 1.6870x; 1.6870x over previous
//
#include <hip/hip_runtime.h>

// ---------------- problem constants ----------------
#define NC    2
#define NB    9
#define NNODE 820
#define NL    3
#define NK    17
#define G     4          // nodes per block
#define NGB   205        // 820 / G

#define EPSF     1e-30f
// scale constant: C = sqrt(log2(e)/2); exp(-d_unscaled^2/2) == exp2(-(d_unscaled*C)^2)
#define C_SCF    0.84932178f
// ISQ2PI / C   (pdf normalization when one 1/sigma factor is C-scaled)
#define KLPN     0.46971920f
// I2PI / C^2   (normalization when two 1/sigma factors are C-scaled)
#define KE       0.22063560f

// output layout (flat f32 offsets, concatenated in reference return order)
#define OFF_XN    0LL
#define OFF_XE    752760LL
#define OFF_LPN   26315388LL
#define OFF_LPE   27068148LL
#define OFF_ALPHA 39849462LL
#define OFF_O1    39849516LL
#define OFF_O2    39893742LL

// ---------------- compile-time Gauss-Hermite nodes (n=17) ----------------
constexpr double csqrt(double v) {
    if (v <= 0.0) return 0.0;
    double y = v > 1.0 ? v : 1.0;
    for (int i = 0; i < 80; ++i) y = 0.5 * (y + v / y);
    return y;
}

struct HNodesF { float x[NK]; };

constexpr HNodesF compute_nodes() {
    const int n = NK;
    const double PIM4 = 0.7511255444649425;   // pi^{-1/4}
    double c1[NK + 1] = {}, c2[NK + 1] = {};
    for (int j = 1; j <= n; ++j) {
        c1[j] = csqrt(2.0 / (double)j);
        c2[j] = csqrt(((double)j - 1.0) / (double)j);
    }
    const double PPC = csqrt(2.0 * (double)n);
    double xr[9] = {};
    double z = 0.0;
    for (int i = 0; i < 9; ++i) {
        if (i == 0)      z = csqrt(2.0 * n + 1.0) - 1.85575 * 0.552905;   // 35^-0.16667
        else if (i == 1) z -= 1.14 * 3.34327 / z;                          // 17^0.426
        else if (i == 2) z = 1.86 * z - 0.86 * xr[0];
        else if (i == 3) z = 1.91 * z - 0.91 * xr[1];
        else             z = 2.0 * z - xr[i - 2];
        for (int it = 0; it < 24; ++it) {
            double p1 = PIM4, p2 = 0.0;
            for (int j = 1; j <= n; ++j) {
                double p3 = p2;
                p2 = p1;
                p1 = z * c1[j] * p2 - c2[j] * p3;
            }
            double pp = PPC * p2;
            double z1 = z;
            z = z1 - p1 / pp;
            double d = z - z1; if (d < 0.0) d = -d;
            if (d <= 3.0e-14) break;
        }
        xr[i] = z;
    }
    HNodesF f{};
    for (int i = 0; i < 9; ++i) {
        f.x[16 - i] = (float)xr[i];
        f.x[i]      = (float)(-xr[i]);
    }
    return f;
}

// (xi*sqrt2, xj*sqrt2) table for q in [0,289): xi = x[q%17], xj = x[q/17]
struct TabF { float v[289 * 2]; };
constexpr TabF make_tab() {
    HNodesF h = compute_nodes();
    TabF t{};
    for (int q = 0; q < 289; ++q) {
        t.v[2 * q]     = (float)((double)h.x[q % 17] * 1.4142135623730951);
        t.v[2 * q + 1] = (float)((double)h.x[q / 17] * 1.4142135623730951);
    }
    return t;
}
constexpr TabF TABC = make_tab();

__device__ __forceinline__ int idOf(int n) {
    if (n < 729) { return 729 + (n / 81) * 9 + (n % 27) / 3; }
    if (n < 810) { int m = n - 729; return 810 + (m / 27) * 3 + (m % 9) / 3; }
    return 819;
}

__device__ __forceinline__ float rcpf(float x) { return __builtin_amdgcn_rcpf(x); }

// ---------------- single fused kernel ----------------
// grid = (205, 18); block (g, cb) handles nodes n0..n0+3 of batch-slice cb.
__global__ __launch_bounds__(256) void fused_kernel(const float* __restrict__ mu,
                                                    const float* __restrict__ sg,
                                                    const float* __restrict__ w,
                                                    float* __restrict__ out) {
    const int g   = blockIdx.x;           // 0..204
    const int cb  = blockIdx.y;           // 0..17
    const int b   = cb % NB;
    const int n0  = g * G;
    const int tid = threadIdx.x;

    __shared__ float2 tab[289];
    {
        const float2* tc = (const float2*)TABC.v;
        tab[tid] = tc[tid];
        if (tid < 33) tab[256 + tid] = tc[256 + tid];
    }

    // softmax alphas (uniform across block)
    const float* wB = w + cb * 3;
    float w0 = wB[0], w1 = wB[1], w2 = wB[2];
    float wm = fmaxf(w0, fmaxf(w1, w2));
    float e0 = __expf(w0 - wm), e1 = __expf(w1 - wm), e2 = __expf(w2 - wm);
    float ainv = 1.0f / (e0 + e1 + e2);
    float a0 = e0 * ainv, a1 = e1 * ainv, a2 = e2 * ainv;

    const size_t cbase = (size_t)cb * NNODE;

    __syncthreads();

    // ---- xn + lpn: threads 0..203 handle (nn, l1, k) = t/51, (t%51)/17, t%17 ----
    if (tid < 204) {
        int nn = tid / 51;
        int r  = tid - 51 * nn;
        int l1 = r / 17;
        int k  = r - 17 * l1;
        int n  = n0 + nn;
        size_t mb = (cbase + n) * 3;
        float ul = mu[mb + l1], sl = sg[mb + l1];
        float xn = fmaf(tab[k].x, sl, ul);      // tab[k].x = node_k * sqrt2
        out[OFF_XN + (cbase + n0) * 51 + tid] = xn;

        float lp = 0.0f;
        if (!(b >= 1 && n < 729)) {
            float ua = mu[mb], ub = mu[mb + 1], uc = mu[mb + 2];
            float ia = C_SCF * rcpf(sg[mb]);
            float ib = C_SCF * rcpf(sg[mb + 1]);
            float ic = C_SCF * rcpf(sg[mb + 2]);
            float d0 = (xn - ua) * ia;
            float d1 = (xn - ub) * ib;
            float d2 = (xn - uc) * ic;
            float sum = a0 * ia * exp2f(-(d0 * d0))
                      + a1 * ib * exp2f(-(d1 * d1))
                      + a2 * ic * exp2f(-(d2 * d2));
            lp = __logf(sum * KLPN + EPSF);
        }
        out[OFF_LPN + (cbase + n0) * 51 + tid] = lp;
    } else if (tid < 216) {           // o1: 4 nodes x 3
        int t = tid - 204; int nn = t / 3, c = t - 3 * nn; int n = n0 + nn;
        if (n < 819) out[OFF_O1 + ((size_t)cb * 819 + n) * 3 + c] = sg[(cbase + n) * 3 + c];
    } else if (tid < 228) {           // o2: 4 nodes x 3 (gathered)
        int t = tid - 216; int nn = t / 3, c = t - 3 * nn; int n = n0 + nn;
        if (n < 819) out[OFF_O2 + ((size_t)cb * 819 + n) * 3 + c] = sg[(cbase + idOf(n)) * 3 + c];
    }

    // ---- alpha (block (0,0), threads 0..53 as extra work) ----
    if (g == 0 && cb == 0 && tid < 54) {
        int cb2 = tid / 3, l = tid - 3 * cb2;
        const float* wB2 = w + cb2 * 3;
        float v0 = wB2[0], v1 = wB2[1], v2 = wB2[2];
        float vm = fmaxf(v0, fmaxf(v1, v2));
        float f0 = __expf(v0 - vm), f1 = __expf(v1 - vm), f2 = __expf(v2 - vm);
        float finv = 1.0f / (f0 + f1 + f2);
        float fl = (l == 0) ? f0 : ((l == 1) ? f1 : f2);
        out[OFF_ALPHA + tid] = fl * finv;
    }

    // ---- edge: xe + lpe, 12 unrolled (nn,l1) sections, q = tid + tails ----
    const int wv = tid >> 6, ln = tid & 63;
    const size_t ecb = (size_t)cb * 819;

#pragma unroll
    for (int nn = 0; nn < G; ++nn) {
        int n = n0 + nn;
        if (n >= 819) continue;
        int idn = idOf(n);
        size_t mb1 = (cbase + n) * 3, mb2 = (cbase + (size_t)idn) * 3;
        float u1a = mu[mb1], u1b = mu[mb1 + 1], u1c = mu[mb1 + 2];
        float s1a = sg[mb1], s1b = sg[mb1 + 1], s1c = sg[mb1 + 2];
        float u2a = mu[mb2], u2b = mu[mb2 + 1], u2c = mu[mb2 + 2];
        float s2a = sg[mb2], s2b = sg[mb2 + 1], s2c = sg[mb2 + 2];
        float i2a = C_SCF * rcpf(s2a), i2b = C_SCF * rcpf(s2b), i2c = C_SCF * rcpf(s2c);

        const bool mk = (b >= 1) && (n < 729);
        float i1a = 0.f, i1b = 0.f, i1c = 0.f, ca, cbv, cc;
        if (mk) {
            ca  = a0 * i2a * KLPN;
            cbv = a1 * i2b * KLPN;
            cc  = a2 * i2c * KLPN;
        } else {
            i1a = C_SCF * rcpf(s1a); i1b = C_SCF * rcpf(s1b); i1c = C_SCF * rcpf(s1c);
            ca  = a0 * i1a * i2a * KE;
            cbv = a1 * i1b * i2b * KE;
            cc  = a2 * i1c * i2c * KE;
        }

        float2* xp0 = reinterpret_cast<float2*>(out + OFF_XE) + (ecb + n) * 867;
        float*  lp0 = out + OFF_LPE + (ecb + n) * 867;

#pragma unroll
        for (int l1 = 0; l1 < 3; ++l1) {
            float u1l = (l1 == 0) ? u1a : ((l1 == 1) ? u1b : u1c);
            float s1l = (l1 == 0) ? s1a : ((l1 == 1) ? s1b : s1c);
            float u2l = (l1 == 0) ? u2a : ((l1 == 1) ? u2b : u2c);
            float s2l = (l1 == 0) ? s2a : ((l1 == 1) ? s2b : s2c);
            float2* xp = xp0 + l1 * 289;
            float*  lp = lp0 + l1 * 289;

            auto body = [&](int q) {
                float2 tv = tab[q];
                float x1 = fmaf(tv.x, s1l, u1l);
                float x2 = fmaf(tv.y, s2l, u2l);
                xp[q] = make_float2(x1, x2);
                float d0 = (x2 - u2a) * i2a;
                float d1 = (x2 - u2b) * i2b;
                float d2 = (x2 - u2c) * i2c;
                float t0 = d0 * d0, t1 = d1 * d1, t2 = d2 * d2;
                if (!mk) {
                    float f0v = (x1 - u1a) * i1a; t0 = fmaf(f0v, f0v, t0);
                    float f1v = (x1 - u1b) * i1b; t1 = fmaf(f1v, f1v, t1);
                    float f2v = (x1 - u1c) * i1c; t2 = fmaf(f2v, f2v, t2);
                }
                float sum = fmaf(cc, exp2f(-t2), fmaf(cbv, exp2f(-t1), ca * exp2f(-t0)));
                lp[q] = __logf(sum + EPSF);
            };

            body(tid);                                 // q in [0,256)
            const int sec = nn * 3 + l1;
            if (wv == (sec & 3) && ln < 33) body(256 + ln);   // q in [256,289)
        }
    }
}

extern "C" void kernel_launch(void* const* d_in, const int* in_sizes, int n_in,
                              void* d_out, int out_size, void* d_ws, size_t ws_size,
                              hipStream_t stream) {
    const float* mu    = (const float*)d_in[0];
    const float* sigma = (const float*)d_in[1];
    const float* w     = (const float*)d_in[2];
    float* out = (float*)d_out;

    hipLaunchKernelGGL(fused_kernel, dim3(NGB, NC * NB), dim3(256), 0, stream,
                       mu, sigma, w, out);
}